// Round 1
// baseline (89.762 us; speedup 1.0000x reference)
//
#include <hip/hip_runtime.h>
#include <math.h>

#define CLS   4096      // row length C
#define KSEL  2048u     // k = round(C * 0.5)
#define TPB   256
#define NCOPY 8         // histogram replication (bank-skewed)

__global__ __launch_bounds__(TPB) void proxy_gate_kernel(
    const float* __restrict__ token,
    const float* __restrict__ proxy,
    float* __restrict__ out)
{
    // LDS: hist 8*257*4 = 8224B, suf 1KB, flags 4KB, misc -> ~13.4KB/block
    __shared__ unsigned s_hist[NCOPY][257];   // +1 skew: copy c of bin b -> bank (b+c)%32
    __shared__ unsigned s_suf[256];
    __shared__ unsigned s_bcast[3];
    __shared__ float    s_fred[8];
    __shared__ unsigned char s_flag[CLS];

    const int row = blockIdx.x;
    const int tid = threadIdx.x;
    const size_t base = (size_t)row * CLS;
    const float4* t4 = (const float4*)(token + base);
    const float4* p4 = (const float4*)(proxy + base);
    float4* o4 = (float4*)(out + base);

    float tok[16], sc[16];
    float sum = 0.f, sumsq = 0.f;

    // ---- single pass load: element j = i*1024 + tid*4 + c ----
    #pragma unroll
    for (int i = 0; i < 4; ++i) {
        float4 t = t4[i*TPB + tid];
        float4 p = p4[i*TPB + tid];
        float a;
        a = fabsf(t.x*p.x); tok[i*4+0]=t.x; sc[i*4+0]=a; sum+=a; sumsq+=a*a;
        a = fabsf(t.y*p.y); tok[i*4+1]=t.y; sc[i*4+1]=a; sum+=a; sumsq+=a*a;
        a = fabsf(t.z*p.z); tok[i*4+2]=t.z; sc[i*4+2]=a; sum+=a; sumsq+=a*a;
        a = fabsf(t.w*p.w); tok[i*4+3]=t.w; sc[i*4+3]=a; sum+=a; sumsq+=a*a;
    }

    // ---- mean / unbiased std ----
    #pragma unroll
    for (int off = 32; off > 0; off >>= 1) {
        sum   += __shfl_xor(sum, off);
        sumsq += __shfl_xor(sumsq, off);
    }
    const int wv = tid >> 6;
    if ((tid & 63) == 0) { s_fred[wv] = sum; s_fred[4+wv] = sumsq; }
    __syncthreads();
    const float tot   = s_fred[0]+s_fred[1]+s_fred[2]+s_fred[3];
    const float totsq = s_fred[4]+s_fred[5]+s_fred[6]+s_fred[7];
    const float mu = tot * (1.0f/CLS);
    float var = (totsq - tot*mu) * (1.0f/(CLS-1));
    var = fmaxf(var, 0.0f);
    const float inv_sigma = 1.0f / fmaxf(sqrtf(var), 1e-6f);

    // ---- exact k-th largest via 4-pass radix select on float bits ----
    // scores are >= 0 so uint bit pattern is value-monotone.
    const int copy = (tid >> 3) & (NCOPY - 1);
    unsigned prefix = 0;
    unsigned kr = KSEL;        // rank remaining within current prefix class
    unsigned cnt_eq = 0;       // after last pass: # elements exactly == threshold

    #pragma unroll
    for (int pass = 0; pass < 4; ++pass) {
        const int sh = 24 - 8*pass;

        unsigned* hflat = (unsigned*)s_hist;
        #pragma unroll
        for (int m = 0; m < (NCOPY*257 + TPB - 1)/TPB; ++m) {
            int idx = m*TPB + tid;
            if (idx < NCOPY*257) hflat[idx] = 0u;
        }
        __syncthreads();

        #pragma unroll
        for (int i = 0; i < 16; ++i) {
            unsigned u = __float_as_uint(sc[i]);
            bool matched = (pass == 0) ? true
                                       : ((u >> (sh+8)) == (prefix >> (sh+8)));
            if (matched) atomicAdd(&s_hist[copy][(u >> sh) & 255u], 1u);
        }
        __syncthreads();

        // per-bin totals, then inclusive suffix sum over 256 bins
        unsigned v = 0;
        #pragma unroll
        for (int c = 0; c < NCOPY; ++c) v += s_hist[c][tid];
        s_suf[tid] = v;
        __syncthreads();
        #pragma unroll
        for (int off = 1; off < 256; off <<= 1) {
            unsigned w = s_suf[tid] + ((tid + off < 256) ? s_suf[tid + off] : 0u);
            __syncthreads();
            s_suf[tid] = w;
            __syncthreads();
        }
        const unsigned suf  = s_suf[tid];
        const unsigned sufn = (tid < 255) ? s_suf[tid+1] : 0u;
        if (suf >= kr && sufn < kr) {      // unique boundary bin
            s_bcast[0] = (unsigned)tid;
            s_bcast[1] = sufn;
            s_bcast[2] = suf - sufn;
        }
        __syncthreads();
        prefix |= s_bcast[0] << sh;
        kr     -= s_bcast[1];
        cnt_eq  = s_bcast[2];
        __syncthreads();
    }

    const float thr = __uint_as_float(prefix);
    // need_eq = kr elements with score == thr get the hard mask (lowest index first).
    const bool tie_rare = (cnt_eq != kr);   // block-uniform

    if (tie_rare) {
        // rank equal-valued elements by global index; select the first kr of them
        #pragma unroll
        for (int i = 0; i < 4; ++i) {
            #pragma unroll
            for (int c2 = 0; c2 < 4; ++c2)
                s_flag[i*1024 + tid*4 + c2] = (sc[i*4+c2] == thr) ? 1 : 0;
        }
        __syncthreads();
        unsigned lc = 0;
        unsigned char mf[16];
        #pragma unroll
        for (int m = 0; m < 16; ++m) { mf[m] = s_flag[tid*16 + m]; lc += mf[m]; }
        s_suf[tid] = lc;
        __syncthreads();
        #pragma unroll
        for (int off = 1; off < 256; off <<= 1) {   // inclusive forward scan
            unsigned w = s_suf[tid] + ((tid >= off) ? s_suf[tid - off] : 0u);
            __syncthreads();
            s_suf[tid] = w;
            __syncthreads();
        }
        unsigned r = s_suf[tid] - lc;               // exclusive prefix (index order)
        #pragma unroll
        for (int m = 0; m < 16; ++m) {
            if (mf[m]) { s_flag[tid*16 + m] = (r < kr) ? 2 : 0; ++r; }
        }
        __syncthreads();
    }

    // ---- gate + store (registers still hold tok/sc) ----
    #pragma unroll
    for (int i = 0; i < 4; ++i) {
        float res[4];
        #pragma unroll
        for (int c2 = 0; c2 < 4; ++c2) {
            const float s = sc[i*4+c2];
            const float z = (s - mu) * inv_sigma;
            const float soft = 1.0f / (1.0f + __expf(-z));
            bool hard;
            if (tie_rare)
                hard = (s > thr) || ((s == thr) && (s_flag[i*1024 + tid*4 + c2] == 2));
            else
                hard = (s >= thr);
            res[c2] = tok[i*4+c2] * (hard ? 1.0f : soft);
        }
        o4[i*TPB + tid] = make_float4(res[0], res[1], res[2], res[3]);
    }
}

extern "C" void kernel_launch(void* const* d_in, const int* in_sizes, int n_in,
                              void* d_out, int out_size, void* d_ws, size_t ws_size,
                              hipStream_t stream) {
    const float* token = (const float*)d_in[0];
    const float* proxy = (const float*)d_in[1];
    float* outp = (float*)d_out;
    const int B = in_sizes[0] / CLS;
    hipLaunchKernelGGL(proxy_gate_kernel, dim3(B), dim3(TPB), 0, stream,
                       token, proxy, outp);
}

// Round 2
// 83.207 us; speedup vs baseline: 1.0788x; 1.0788x over previous
//
#include <hip/hip_runtime.h>
#include <math.h>

#define CLS   4096      // row length C
#define KSEL  2048u     // k = round(C * 0.5)
#define TPB   256
#define NCOPY 8         // histogram replication (bank-skewed)

__global__ __launch_bounds__(TPB) void proxy_gate_kernel(
    const float* __restrict__ token,
    const float* __restrict__ proxy,
    float* __restrict__ out)
{
    __shared__ unsigned s_hist[NCOPY][257];   // +1 skew: copy c of bin b -> bank (b+c)%32
    __shared__ unsigned s_suf[256];           // rare tie path only
    __shared__ unsigned s_wt[4];              // per-wave totals
    __shared__ unsigned s_bcast[3];
    __shared__ float    s_fred[8];
    __shared__ unsigned char s_flag[CLS];

    const int row = blockIdx.x;
    const int tid = threadIdx.x;
    const int lane = tid & 63;
    const int wv = tid >> 6;
    const size_t base = (size_t)row * CLS;
    const float4* t4 = (const float4*)(token + base);
    const float4* p4 = (const float4*)(proxy + base);
    float4* o4 = (float4*)(out + base);

    float tok[16], sc[16];
    float sum = 0.f, sumsq = 0.f;

    // ---- single-pass load: element j = i*1024 + tid*4 + c ----
    #pragma unroll
    for (int i = 0; i < 4; ++i) {
        float4 t = t4[i*TPB + tid];
        float4 p = p4[i*TPB + tid];
        float a;
        a = fabsf(t.x*p.x); tok[i*4+0]=t.x; sc[i*4+0]=a; sum+=a; sumsq+=a*a;
        a = fabsf(t.y*p.y); tok[i*4+1]=t.y; sc[i*4+1]=a; sum+=a; sumsq+=a*a;
        a = fabsf(t.z*p.z); tok[i*4+2]=t.z; sc[i*4+2]=a; sum+=a; sumsq+=a*a;
        a = fabsf(t.w*p.w); tok[i*4+3]=t.w; sc[i*4+3]=a; sum+=a; sumsq+=a*a;
    }

    // ---- mean / unbiased std ----
    #pragma unroll
    for (int off = 32; off > 0; off >>= 1) {
        sum   += __shfl_xor(sum, off);
        sumsq += __shfl_xor(sumsq, off);
    }
    if (lane == 0) { s_fred[wv] = sum; s_fred[4+wv] = sumsq; }
    __syncthreads();
    const float tot   = s_fred[0]+s_fred[1]+s_fred[2]+s_fred[3];
    const float totsq = s_fred[4]+s_fred[5]+s_fred[6]+s_fred[7];
    const float mu = tot * (1.0f/CLS);
    float var = (totsq - tot*mu) * (1.0f/(CLS-1));
    var = fmaxf(var, 0.0f);
    const float inv_sigma = 1.0f / fmaxf(sqrtf(var), 1e-6f);

    // ---- exact k-th largest via 4-pass radix select on float bits ----
    // scores >= 0 so the uint bit pattern is value-monotone.
    const int copy = (tid >> 3) & (NCOPY - 1);
    unsigned prefix = 0;
    unsigned kr = KSEL;        // rank remaining within current prefix class
    unsigned cnt_eq = 0;       // after last pass: # elements exactly == threshold

    #pragma unroll
    for (int pass = 0; pass < 4; ++pass) {
        const int sh = 24 - 8*pass;

        unsigned* hflat = (unsigned*)s_hist;
        #pragma unroll
        for (int m = 0; m < (NCOPY*257 + TPB - 1)/TPB; ++m) {
            int idx = m*TPB + tid;
            if (idx < NCOPY*257) hflat[idx] = 0u;
        }
        __syncthreads();                               // B1

        #pragma unroll
        for (int i = 0; i < 16; ++i) {
            unsigned u = __float_as_uint(sc[i]);
            bool matched = (pass == 0) ? true
                                       : ((u >> (sh+8)) == (prefix >> (sh+8)));
            if (matched) atomicAdd(&s_hist[copy][(u >> sh) & 255u], 1u);
        }
        __syncthreads();                               // B2

        // thread tid owns bin tid: gather replicated copies
        unsigned v = 0;
        #pragma unroll
        for (int c = 0; c < NCOPY; ++c) v += s_hist[c][tid];

        // wave-level inclusive SUFFIX scan over the 64 bins this wave owns
        unsigned s = v;
        #pragma unroll
        for (int off = 1; off < 64; off <<= 1) {
            unsigned t = __shfl_down(s, off);
            if (lane + off < 64) s += t;
        }
        if (lane == 0) s_wt[wv] = s;                   // wave total
        __syncthreads();                               // B3

        unsigned addhi = 0;
        #pragma unroll
        for (int w2 = 0; w2 < 4; ++w2) if (w2 > wv) addhi += s_wt[w2];
        const unsigned suf  = s + addhi;               // suffix incl. own bin
        const unsigned sufn = suf - v;                 // suffix excl. own bin
        if (suf >= kr && sufn < kr) {                  // unique boundary bin
            s_bcast[0] = (unsigned)tid;
            s_bcast[1] = sufn;
            s_bcast[2] = v;
        }
        __syncthreads();                               // B4
        prefix |= s_bcast[0] << sh;
        kr     -= s_bcast[1];
        cnt_eq  = s_bcast[2];
    }

    const float thr = __uint_as_float(prefix);
    // kr elements with score == thr get the hard mask (lowest index first).
    const bool tie_rare = (cnt_eq != kr);   // block-uniform

    if (tie_rare) {
        // rank equal-valued elements by global index; select the first kr of them
        #pragma unroll
        for (int i = 0; i < 4; ++i) {
            #pragma unroll
            for (int c2 = 0; c2 < 4; ++c2)
                s_flag[i*1024 + tid*4 + c2] = (sc[i*4+c2] == thr) ? 1 : 0;
        }
        __syncthreads();
        unsigned lc = 0;
        unsigned char mf[16];
        #pragma unroll
        for (int m = 0; m < 16; ++m) { mf[m] = s_flag[tid*16 + m]; lc += mf[m]; }
        s_suf[tid] = lc;
        __syncthreads();
        #pragma unroll
        for (int off = 1; off < 256; off <<= 1) {   // inclusive forward scan
            unsigned w = s_suf[tid] + ((tid >= off) ? s_suf[tid - off] : 0u);
            __syncthreads();
            s_suf[tid] = w;
            __syncthreads();
        }
        unsigned r = s_suf[tid] - lc;               // exclusive prefix (index order)
        #pragma unroll
        for (int m = 0; m < 16; ++m) {
            if (mf[m]) { s_flag[tid*16 + m] = (r < kr) ? 2 : 0; ++r; }
        }
        __syncthreads();
    }

    // ---- gate + store (registers still hold tok/sc) ----
    #pragma unroll
    for (int i = 0; i < 4; ++i) {
        float res[4];
        #pragma unroll
        for (int c2 = 0; c2 < 4; ++c2) {
            const float s = sc[i*4+c2];
            const float z = (s - mu) * inv_sigma;
            const float soft = 1.0f / (1.0f + __expf(-z));
            bool hard;
            if (tie_rare)
                hard = (s > thr) || ((s == thr) && (s_flag[i*1024 + tid*4 + c2] == 2));
            else
                hard = (s >= thr);
            res[c2] = tok[i*4+c2] * (hard ? 1.0f : soft);
        }
        o4[i*TPB + tid] = make_float4(res[0], res[1], res[2], res[3]);
    }
}

extern "C" void kernel_launch(void* const* d_in, const int* in_sizes, int n_in,
                              void* d_out, int out_size, void* d_ws, size_t ws_size,
                              hipStream_t stream) {
    const float* token = (const float*)d_in[0];
    const float* proxy = (const float*)d_in[1];
    float* outp = (float*)d_out;
    const int B = in_sizes[0] / CLS;
    hipLaunchKernelGGL(proxy_gate_kernel, dim3(B), dim3(TPB), 0, stream,
                       token, proxy, outp);
}